// Round 1
// baseline (489.252 us; speedup 1.0000x reference)
//
#include <hip/hip_runtime.h>

#define NB 4
#define NC 256
#define NCK 32
#define NPIX 4096

typedef unsigned short u16;
typedef unsigned int u32;
typedef __bf16 bfv8 __attribute__((ext_vector_type(8)));
typedef float f32x4 __attribute__((ext_vector_type(4)));

__device__ inline u16 f2bf(float f) {
  union { float f; u32 u; } v; v.f = f;
  u32 r = v.u + 0x7fffu + ((v.u >> 16) & 1u);  // RNE
  return (u16)(r >> 16);
}

// ---------------- K1: convert Wh (fp32 256x256) -> bf16 ----------------
__global__ __launch_bounds__(256) void k_convert_wh(const float* __restrict__ Wh,
                                                    u16* __restrict__ Whbf) {
  int i = (blockIdx.x * 256 + threadIdx.x) * 4;
  float4 v = *(const float4*)(Wh + i);
  u32 lo = (u32)f2bf(v.x) | ((u32)f2bf(v.y) << 16);
  u32 hi = (u32)f2bf(v.z) | ((u32)f2bf(v.w) << 16);
  *(uint2*)(Whbf + i) = make_uint2(lo, hi);
}

// ---------------- K2: transpose x [B,C,N] fp32 -> xT [B,N,C] bf16 ----------------
__global__ __launch_bounds__(256) void k_transpose(const float* __restrict__ x,
                                                   u16* __restrict__ xT) {
  __shared__ float tile[64][65];
  int blk = blockIdx.x;
  int b = blk >> 8, r = blk & 255;
  int nt = r >> 2, ct = r & 3;
  int t = threadIdx.x;
  int cc = t >> 2, part = t & 3;
  const float* src = x + ((size_t)(b * NC + ct * 64 + cc)) * NPIX + nt * 64 + part * 16;
#pragma unroll
  for (int v = 0; v < 4; v++) {
    float4 d = *(const float4*)(src + v * 4);
    tile[cc][part * 16 + v * 4 + 0] = d.x;
    tile[cc][part * 16 + v * 4 + 1] = d.y;
    tile[cc][part * 16 + v * 4 + 2] = d.z;
    tile[cc][part * 16 + v * 4 + 3] = d.w;
  }
  __syncthreads();
  int n = t >> 2;
  u32 uu[8];
#pragma unroll
  for (int q = 0; q < 8; q++) {
    u16 e0 = f2bf(tile[part * 16 + 2 * q + 0][n]);
    u16 e1 = f2bf(tile[part * 16 + 2 * q + 1][n]);
    uu[q] = (u32)e0 | ((u32)e1 << 16);
  }
  u16* dst = xT + ((size_t)(b * NPIX + nt * 64 + n)) * NC + ct * 64 + part * 16;
  *(uint4*)(dst) = make_uint4(uu[0], uu[1], uu[2], uu[3]);
  *(uint4*)(dst + 8) = make_uint4(uu[4], uu[5], uu[6], uu[7]);
}

// ---------------- K3: f,g projections (fp32 vector GEMM) ----------------
// f[b][k][n], g[b][k][n] = sum_c W[k][c]*x[b][c][n] + bias
__global__ __launch_bounds__(256) void k_fg(const float* __restrict__ x,
                                            const float* __restrict__ Wf,
                                            const float* __restrict__ bf_,
                                            const float* __restrict__ Wg,
                                            const float* __restrict__ bg_,
                                            float* __restrict__ f,
                                            float* __restrict__ g) {
  __shared__ float Wt[256][65];  // Wt[c][o], o<32 -> Wf, else Wg
  __shared__ float xl[32][64];
  int blk = blockIdx.x;
  int b = blk >> 6;
  int n0 = (blk & 63) * 64;
  int t = threadIdx.x;
  int tx = t & 15, ty = t >> 4;
  for (int r = 0; r < 64; r++) {
    // e = r*256 + t : o = r, c = t
    float w = (r < 32) ? Wf[r * 256 + t] : Wg[(r - 32) * 256 + t];
    Wt[t][r] = w;
  }
  float acc[4][4] = {};
  for (int kc = 0; kc < 8; kc++) {
    __syncthreads();
#pragma unroll
    for (int r = 0; r < 2; r++) {
      int e = (r * 256 + t) * 4;
      int row = e >> 6, col = e & 63;
      *(float4*)&xl[row][col] =
          *(const float4*)(x + ((size_t)(b * NC + kc * 32 + row)) * NPIX + n0 + col);
    }
    __syncthreads();
#pragma unroll
    for (int kk = 0; kk < 32; kk++) {
      float4 xv = *(const float4*)&xl[kk][tx * 4];
      float w0 = Wt[kc * 32 + kk][ty * 4 + 0];
      float w1 = Wt[kc * 32 + kk][ty * 4 + 1];
      float w2 = Wt[kc * 32 + kk][ty * 4 + 2];
      float w3 = Wt[kc * 32 + kk][ty * 4 + 3];
      acc[0][0] += w0 * xv.x; acc[0][1] += w0 * xv.y; acc[0][2] += w0 * xv.z; acc[0][3] += w0 * xv.w;
      acc[1][0] += w1 * xv.x; acc[1][1] += w1 * xv.y; acc[1][2] += w1 * xv.z; acc[1][3] += w1 * xv.w;
      acc[2][0] += w2 * xv.x; acc[2][1] += w2 * xv.y; acc[2][2] += w2 * xv.z; acc[2][3] += w2 * xv.w;
      acc[3][0] += w3 * xv.x; acc[3][1] += w3 * xv.y; acc[3][2] += w3 * xv.z; acc[3][3] += w3 * xv.w;
    }
  }
#pragma unroll
  for (int j = 0; j < 4; j++) {
    int o = ty * 4 + j;
    float bias = (o < 32) ? bf_[o] : bg_[o - 32];
    float* dst = ((o < 32) ? f : g) + ((size_t)(b * NCK + (o & 31))) * NPIX + n0 + tx * 4;
    float4 v;
    v.x = acc[j][0] + bias; v.y = acc[j][1] + bias;
    v.z = acc[j][2] + bias; v.w = acc[j][3] + bias;
    *(float4*)dst = v;
  }
}

// ---------------- K4: h projection (bf16 MFMA GEMM) ----------------
// h[b][o][n] bf16 = sum_c Wh[o][c]*x[b][c][n] + bh[o]
// D[m=pixel][n=o]; A = xT rows (K-contig), B = Whbf rows (K-contig)
__global__ __launch_bounds__(256) void k_h(const u16* __restrict__ xT,
                                           const u16* __restrict__ Whbf,
                                           const float* __restrict__ bh,
                                           u16* __restrict__ h) {
  __shared__ u16 At[128 * 32];
  __shared__ u16 Bt[128 * 32];
  int blk = blockIdx.x;
  int b = blk >> 6, r = blk & 63;
  int nt = r >> 1, ot = r & 1;
  int n0 = nt * 128, o0 = ot * 128;
  int t = threadIdx.x, lane = t & 63, w = t >> 6;
  int wr = w >> 1, wc = w & 1;
  int coll = lane & 15, cg = lane >> 4;
  f32x4 acc[4][4] = {};
  for (int kc = 0; kc < 8; kc++) {
    __syncthreads();
#pragma unroll
    for (int r2 = 0; r2 < 2; r2++) {
      int s = r2 * 256 + t;
      int row = s >> 2, slot = s & 3;
      int sw = (row ^ (row >> 2)) & 3;
      uint4 va = *(const uint4*)(xT + ((size_t)(b * NPIX + n0 + row)) * NC + kc * 32 + slot * 8);
      *(uint4*)((char*)At + row * 64 + ((slot ^ sw) * 16)) = va;
      uint4 vb = *(const uint4*)(Whbf + (size_t)(o0 + row) * NC + kc * 32 + slot * 8);
      *(uint4*)((char*)Bt + row * 64 + ((slot ^ sw) * 16)) = vb;
    }
    __syncthreads();
    bfv8 af[4], bfr[4];
#pragma unroll
    for (int mi = 0; mi < 4; mi++) {
      int row = wr * 64 + mi * 16 + coll;
      int slot = cg ^ ((row ^ (row >> 2)) & 3);
      af[mi] = *(const bfv8*)((const char*)At + row * 64 + slot * 16);
    }
#pragma unroll
    for (int ni = 0; ni < 4; ni++) {
      int row = wc * 64 + ni * 16 + coll;
      int slot = cg ^ ((row ^ (row >> 2)) & 3);
      bfr[ni] = *(const bfv8*)((const char*)Bt + row * 64 + slot * 16);
    }
#pragma unroll
    for (int mi = 0; mi < 4; mi++)
#pragma unroll
      for (int ni = 0; ni < 4; ni++)
        acc[mi][ni] = __builtin_amdgcn_mfma_f32_16x16x32_bf16(af[mi], bfr[ni], acc[mi][ni], 0, 0, 0);
  }
#pragma unroll
  for (int ni = 0; ni < 4; ni++) {
    int o = o0 + wc * 64 + ni * 16 + coll;
    float bias = bh[o];
#pragma unroll
    for (int mi = 0; mi < 4; mi++) {
      int px = n0 + wr * 64 + mi * 16 + cg * 4;
      u32 lo = (u32)f2bf(acc[mi][ni][0] + bias) | ((u32)f2bf(acc[mi][ni][1] + bias) << 16);
      u32 hi = (u32)f2bf(acc[mi][ni][2] + bias) | ((u32)f2bf(acc[mi][ni][3] + bias) << 16);
      *(uint2*)(h + ((size_t)(b * NC + o)) * NPIX + px) = make_uint2(lo, hi);
    }
  }
}

// ---------------- shared QK^T inner loop ----------------
__device__ inline void qk_dot(const float (&kt)[32][64], const float* q, int cg, float* s) {
#pragma unroll
  for (int c = 0; c < 16; c++) s[c] = 0.f;
#pragma unroll
  for (int k = 0; k < 32; k++) {
    float qk = q[k];
    float4 v0 = *(const float4*)&kt[k][cg * 16 + 0];
    float4 v1 = *(const float4*)&kt[k][cg * 16 + 4];
    float4 v2 = *(const float4*)&kt[k][cg * 16 + 8];
    float4 v3 = *(const float4*)&kt[k][cg * 16 + 12];
    s[0] += qk * v0.x;  s[1] += qk * v0.y;  s[2] += qk * v0.z;  s[3] += qk * v0.w;
    s[4] += qk * v1.x;  s[5] += qk * v1.y;  s[6] += qk * v1.z;  s[7] += qk * v1.w;
    s[8] += qk * v2.x;  s[9] += qk * v2.y;  s[10] += qk * v2.z; s[11] += qk * v2.w;
    s[12] += qk * v3.x; s[13] += qk * v3.y; s[14] += qk * v3.z; s[15] += qk * v3.w;
  }
}

// ---------------- K5: pass 1 — per-row j: M_j = max_i S'[j,i], Dinv_j ----------------
// S'[j,i] = sum_k f[k,j] g[k,i]
__global__ __launch_bounds__(256) void k_pass1(const float* __restrict__ f,
                                               const float* __restrict__ g,
                                               float* __restrict__ Mrow,
                                               float* __restrict__ Dinv) {
  __shared__ float qlds[32][64];
  __shared__ float kt[32][64];
  int blk = blockIdx.x;
  int b = blk >> 6;
  int j0 = (blk & 63) * 64;
  int t = threadIdx.x, lane = t & 63, w = t >> 6;
  int coll = lane & 15, cg = lane >> 4;
#pragma unroll
  for (int r = 0; r < 2; r++) {
    int e = (r * 256 + t) * 4;
    int row = e >> 6, col = e & 63;
    *(float4*)&qlds[row][col] = *(const float4*)(f + ((size_t)(b * NCK + row)) * NPIX + j0 + col);
  }
  __syncthreads();
  int myrow = w * 16 + coll;
  float q[32];
#pragma unroll
  for (int k = 0; k < 32; k++) q[k] = qlds[k][myrow];
  float m = -3.0e38f, d = 0.f;
  for (int it = 0; it < 64; it++) {
    __syncthreads();
#pragma unroll
    for (int r = 0; r < 2; r++) {
      int e = (r * 256 + t) * 4;
      int row = e >> 6, col = e & 63;
      *(float4*)&kt[row][col] = *(const float4*)(g + ((size_t)(b * NCK + row)) * NPIX + it * 64 + col);
    }
    __syncthreads();
    float s[16];
    qk_dot(kt, q, cg, s);
    float ms = s[0];
#pragma unroll
    for (int c = 1; c < 16; c++) ms = fmaxf(ms, s[c]);
    float nm = fmaxf(m, ms);
    float sum = 0.f;
#pragma unroll
    for (int c = 0; c < 16; c++) sum += __expf(s[c] - nm);
    d = d * __expf(m - nm) + sum;
    m = nm;
  }
  float m2 = __shfl_xor(m, 16);
  float d2 = __shfl_xor(d, 16);
  float nm = fmaxf(m, m2);
  d = d * __expf(m - nm) + d2 * __expf(m2 - nm);
  m = nm;
  m2 = __shfl_xor(m, 32);
  d2 = __shfl_xor(d, 32);
  nm = fmaxf(m, m2);
  d = d * __expf(m - nm) + d2 * __expf(m2 - nm);
  m = nm;
  if (cg == 0) {
    int j = b * NPIX + j0 + myrow;
    Mrow[j] = m;
    Dinv[j] = 1.0f / d;
  }
}

// ---------------- K6: pass 2 — O[i,c] = sum_j exp(S'[j,i]-M_j)*Dinv_j * h[c,j]; out = gamma*O + x
__global__ __launch_bounds__(256) void k_pass2(const float* __restrict__ g,
                                               const float* __restrict__ f,
                                               const u16* __restrict__ h,
                                               const float* __restrict__ Mrow,
                                               const float* __restrict__ Dinv,
                                               const float* __restrict__ x,
                                               const float* __restrict__ gamma,
                                               float* __restrict__ out) {
  __shared__ float qlds[32][64];
  __shared__ float kt[32][64];
  __shared__ float md[2][64];
  __shared__ u16 vt[256 * 64];
  __shared__ u16 pl[4][16 * 64];
  __shared__ float tb[64][65];
  int blk = blockIdx.x;
  int b = blk >> 6;
  int i0 = (blk & 63) * 64;
  int t = threadIdx.x, lane = t & 63, w = t >> 6;
  int coll = lane & 15, cg = lane >> 4;
#pragma unroll
  for (int r = 0; r < 2; r++) {
    int e = (r * 256 + t) * 4;
    int row = e >> 6, col = e & 63;
    *(float4*)&qlds[row][col] = *(const float4*)(g + ((size_t)(b * NCK + row)) * NPIX + i0 + col);
  }
  __syncthreads();
  int myrow = w * 16 + coll;
  float q[32];
#pragma unroll
  for (int k = 0; k < 32; k++) q[k] = qlds[k][myrow];
  f32x4 acc[16] = {};
  for (int jt = 0; jt < 64; jt++) {
    int j0 = jt * 64;
    __syncthreads();
#pragma unroll
    for (int r = 0; r < 2; r++) {
      int e = (r * 256 + t) * 4;
      int row = e >> 6, col = e & 63;
      *(float4*)&kt[row][col] = *(const float4*)(f + ((size_t)(b * NCK + row)) * NPIX + j0 + col);
    }
    if (t < 64) {
      md[0][t] = Mrow[b * NPIX + j0 + t];
      md[1][t] = Dinv[b * NPIX + j0 + t];
    }
#pragma unroll
    for (int r2 = 0; r2 < 8; r2++) {
      int sidx = r2 * 256 + t;
      int row = sidx >> 3, slot = sidx & 7;
      int sw = (row ^ (row >> 3)) & 7;
      uint4 v = *(const uint4*)(h + ((size_t)(b * NC + row)) * NPIX + j0 + slot * 8);
      *(uint4*)((char*)vt + row * 128 + ((slot ^ sw) * 16)) = v;
    }
    __syncthreads();
    float s[16];
    qk_dot(kt, q, cg, s);
    u32 uu[8];
#pragma unroll
    for (int qq = 0; qq < 8; qq++) {
      float p0 = __expf(s[2 * qq + 0] - md[0][cg * 16 + 2 * qq + 0]) * md[1][cg * 16 + 2 * qq + 0];
      float p1 = __expf(s[2 * qq + 1] - md[0][cg * 16 + 2 * qq + 1]) * md[1][cg * 16 + 2 * qq + 1];
      uu[qq] = (u32)f2bf(p0) | ((u32)f2bf(p1) << 16);
    }
    char* pbase = (char*)&pl[w][0] + coll * 128;
    *(uint4*)(pbase + (((cg * 2 + 0) ^ (coll & 7)) * 16)) = make_uint4(uu[0], uu[1], uu[2], uu[3]);
    *(uint4*)(pbase + (((cg * 2 + 1) ^ (coll & 7)) * 16)) = make_uint4(uu[4], uu[5], uu[6], uu[7]);
    bfv8 pa[2];
#pragma unroll
    for (int kb = 0; kb < 2; kb++) {
      int slot = kb * 4 + cg;
      pa[kb] = *(const bfv8*)((const char*)&pl[w][0] + coll * 128 + ((slot ^ (coll & 7)) * 16));
    }
#pragma unroll
    for (int ct = 0; ct < 16; ct++) {
      int row = ct * 16 + coll;
      int sw8 = (row ^ (row >> 3)) & 7;
#pragma unroll
      for (int kb = 0; kb < 2; kb++) {
        bfv8 bv = *(const bfv8*)((const char*)vt + row * 128 + (((kb * 4 + cg) ^ sw8) * 16));
        acc[ct] = __builtin_amdgcn_mfma_f32_16x16x32_bf16(pa[kb], bv, acc[ct], 0, 0, 0);
      }
    }
  }
  float gam = gamma[0];
  for (int ch = 0; ch < 4; ch++) {
    __syncthreads();
#pragma unroll
    for (int q2 = 0; q2 < 4; q2++)
#pragma unroll
      for (int rr = 0; rr < 4; rr++)
        tb[w * 16 + cg * 4 + rr][q2 * 16 + coll] = acc[ch * 4 + q2][rr];
    __syncthreads();
    int crow = t >> 2, part = t & 3;
    const float* xp = x + ((size_t)(b * NC + ch * 64 + crow)) * NPIX + i0 + part * 16;
    float* op = out + ((size_t)(b * NC + ch * 64 + crow)) * NPIX + i0 + part * 16;
#pragma unroll
    for (int v = 0; v < 4; v++) {
      float4 xv = *(const float4*)(xp + v * 4);
      float4 ov;
      ov.x = gam * tb[part * 16 + v * 4 + 0][crow] + xv.x;
      ov.y = gam * tb[part * 16 + v * 4 + 1][crow] + xv.y;
      ov.z = gam * tb[part * 16 + v * 4 + 2][crow] + xv.z;
      ov.w = gam * tb[part * 16 + v * 4 + 3][crow] + xv.w;
      *(float4*)(op + v * 4) = ov;
    }
  }
}

extern "C" void kernel_launch(void* const* d_in, const int* in_sizes, int n_in,
                              void* d_out, int out_size, void* d_ws, size_t ws_size,
                              hipStream_t stream) {
  (void)in_sizes; (void)n_in; (void)out_size; (void)ws_size;
  const float* x = (const float*)d_in[0];
  const float* Wf = (const float*)d_in[1];
  const float* bf_ = (const float*)d_in[2];
  const float* Wg = (const float*)d_in[3];
  const float* bg_ = (const float*)d_in[4];
  const float* Wh = (const float*)d_in[5];
  const float* bh = (const float*)d_in[6];
  const float* gamma = (const float*)d_in[7];
  float* out = (float*)d_out;
  char* ws = (char*)d_ws;
  u16* xT = (u16*)ws;                                   // 8 MB
  u16* h = (u16*)(ws + (8u << 20));                     // 8 MB
  float* f = (float*)(ws + (16u << 20));                // 2 MB
  float* g = (float*)(ws + (18u << 20));                // 2 MB
  float* Mrow = (float*)(ws + (20u << 20));             // 64 KB
  float* Dinv = (float*)(ws + (20u << 20) + 65536);     // 64 KB
  u16* Whbf = (u16*)(ws + (20u << 20) + 131072);        // 128 KB

  k_convert_wh<<<64, 256, 0, stream>>>(Wh, Whbf);
  k_transpose<<<1024, 256, 0, stream>>>(x, xT);
  k_fg<<<256, 256, 0, stream>>>(x, Wf, bf_, Wg, bg_, f, g);
  k_h<<<256, 256, 0, stream>>>(xT, Whbf, bh, h);
  k_pass1<<<256, 256, 0, stream>>>(f, g, Mrow, Dinv);
  k_pass2<<<256, 256, 0, stream>>>(g, f, h, Mrow, Dinv, x, gamma, out);
}

// Round 2
// 310.409 us; speedup vs baseline: 1.5762x; 1.5762x over previous
//
#include <hip/hip_runtime.h>

#define NB 4
#define NC 256
#define NCK 32
#define NPIX 4096

typedef unsigned short u16;
typedef unsigned int u32;
typedef __bf16 bfv8 __attribute__((ext_vector_type(8)));
typedef float f32x4 __attribute__((ext_vector_type(4)));

__device__ inline u16 f2bf(float f) {
  union { float f; u32 u; } v; v.f = f;
  u32 r = v.u + 0x7fffu + ((v.u >> 16) & 1u);  // RNE
  return (u16)(r >> 16);
}
__device__ inline float bf2f(u16 h) {
  union { u32 u; float f; } v; v.u = (u32)h << 16; return v.f;
}

// ---------------- K1: convert Wh (fp32 256x256) -> bf16 ----------------
__global__ __launch_bounds__(256) void k_convert_wh(const float* __restrict__ Wh,
                                                    u16* __restrict__ Whbf) {
  int i = (blockIdx.x * 256 + threadIdx.x) * 4;
  float4 v = *(const float4*)(Wh + i);
  u32 lo = (u32)f2bf(v.x) | ((u32)f2bf(v.y) << 16);
  u32 hi = (u32)f2bf(v.z) | ((u32)f2bf(v.w) << 16);
  *(uint2*)(Whbf + i) = make_uint2(lo, hi);
}

// ---------------- K2: transpose x [B,C,N] fp32 -> xT [B,N,C] bf16 ----------------
__global__ __launch_bounds__(256) void k_transpose(const float* __restrict__ x,
                                                   u16* __restrict__ xT) {
  __shared__ float tile[64][65];
  int blk = blockIdx.x;
  int b = blk >> 8, r = blk & 255;
  int nt = r >> 2, ct = r & 3;
  int t = threadIdx.x;
  int cc = t >> 2, part = t & 3;
  const float* src = x + ((size_t)(b * NC + ct * 64 + cc)) * NPIX + nt * 64 + part * 16;
#pragma unroll
  for (int v = 0; v < 4; v++) {
    float4 d = *(const float4*)(src + v * 4);
    tile[cc][part * 16 + v * 4 + 0] = d.x;
    tile[cc][part * 16 + v * 4 + 1] = d.y;
    tile[cc][part * 16 + v * 4 + 2] = d.z;
    tile[cc][part * 16 + v * 4 + 3] = d.w;
  }
  __syncthreads();
  int n = t >> 2;
  u32 uu[8];
#pragma unroll
  for (int q = 0; q < 8; q++) {
    u16 e0 = f2bf(tile[part * 16 + 2 * q + 0][n]);
    u16 e1 = f2bf(tile[part * 16 + 2 * q + 1][n]);
    uu[q] = (u32)e0 | ((u32)e1 << 16);
  }
  u16* dst = xT + ((size_t)(b * NPIX + nt * 64 + n)) * NC + ct * 64 + part * 16;
  *(uint4*)(dst) = make_uint4(uu[0], uu[1], uu[2], uu[3]);
  *(uint4*)(dst + 8) = make_uint4(uu[4], uu[5], uu[6], uu[7]);
}

// ---------------- K3: f,g projections -> packed hi/lo bf16, K-contiguous ----------------
// fT[b][n][0:32]=hi(f[k,n]), [32:64]=lo ; gT likewise
__global__ __launch_bounds__(256) void k_fg(const float* __restrict__ x,
                                            const float* __restrict__ Wf,
                                            const float* __restrict__ bf_,
                                            const float* __restrict__ Wg,
                                            const float* __restrict__ bg_,
                                            u16* __restrict__ fT,
                                            u16* __restrict__ gT) {
  __shared__ float Wt[256][65];  // Wt[c][o], o<32 -> Wf, else Wg
  __shared__ float xl[32][64];
  __shared__ float tb[64][68];   // [n][o] result staging
  int blk = blockIdx.x;
  int b = blk >> 6;
  int n0 = (blk & 63) * 64;
  int t = threadIdx.x;
  int tx = t & 15, ty = t >> 4;
  for (int r = 0; r < 64; r++) {
    float w = (r < 32) ? Wf[r * 256 + t] : Wg[(r - 32) * 256 + t];
    Wt[t][r] = w;
  }
  float acc[4][4] = {};
  for (int kc = 0; kc < 8; kc++) {
    __syncthreads();
#pragma unroll
    for (int r = 0; r < 2; r++) {
      int e = (r * 256 + t) * 4;
      int row = e >> 6, col = e & 63;
      *(float4*)&xl[row][col] =
          *(const float4*)(x + ((size_t)(b * NC + kc * 32 + row)) * NPIX + n0 + col);
    }
    __syncthreads();
#pragma unroll
    for (int kk = 0; kk < 32; kk++) {
      float4 xv = *(const float4*)&xl[kk][tx * 4];
      float w0 = Wt[kc * 32 + kk][ty * 4 + 0];
      float w1 = Wt[kc * 32 + kk][ty * 4 + 1];
      float w2 = Wt[kc * 32 + kk][ty * 4 + 2];
      float w3 = Wt[kc * 32 + kk][ty * 4 + 3];
      acc[0][0] += w0 * xv.x; acc[0][1] += w0 * xv.y; acc[0][2] += w0 * xv.z; acc[0][3] += w0 * xv.w;
      acc[1][0] += w1 * xv.x; acc[1][1] += w1 * xv.y; acc[1][2] += w1 * xv.z; acc[1][3] += w1 * xv.w;
      acc[2][0] += w2 * xv.x; acc[2][1] += w2 * xv.y; acc[2][2] += w2 * xv.z; acc[2][3] += w2 * xv.w;
      acc[3][0] += w3 * xv.x; acc[3][1] += w3 * xv.y; acc[3][2] += w3 * xv.z; acc[3][3] += w3 * xv.w;
    }
  }
#pragma unroll
  for (int j = 0; j < 4; j++) {
    int o = ty * 4 + j;
    float bias = (o < 32) ? bf_[o] : bg_[o - 32];
#pragma unroll
    for (int vi = 0; vi < 4; vi++) tb[tx * 4 + vi][o] = acc[j][vi] + bias;
  }
  __syncthreads();
  int n = t >> 2, part = t & 3;
  // f half (o 0..31)
  {
    u32 ph[4], plo[4];
#pragma unroll
    for (int e = 0; e < 4; e++) {
      float v0 = tb[n][part * 8 + 2 * e + 0];
      float v1 = tb[n][part * 8 + 2 * e + 1];
      u16 h0 = f2bf(v0), h1 = f2bf(v1);
      u16 l0 = f2bf(v0 - bf2f(h0)), l1 = f2bf(v1 - bf2f(h1));
      ph[e] = (u32)h0 | ((u32)h1 << 16);
      plo[e] = (u32)l0 | ((u32)l1 << 16);
    }
    u16* dst = fT + ((size_t)(b * NPIX) + n0 + n) * 64 + part * 8;
    *(uint4*)dst = make_uint4(ph[0], ph[1], ph[2], ph[3]);
    *(uint4*)(dst + 32) = make_uint4(plo[0], plo[1], plo[2], plo[3]);
  }
  // g half (o 32..63)
  {
    u32 ph[4], plo[4];
#pragma unroll
    for (int e = 0; e < 4; e++) {
      float v0 = tb[n][32 + part * 8 + 2 * e + 0];
      float v1 = tb[n][32 + part * 8 + 2 * e + 1];
      u16 h0 = f2bf(v0), h1 = f2bf(v1);
      u16 l0 = f2bf(v0 - bf2f(h0)), l1 = f2bf(v1 - bf2f(h1));
      ph[e] = (u32)h0 | ((u32)h1 << 16);
      plo[e] = (u32)l0 | ((u32)l1 << 16);
    }
    u16* dst = gT + ((size_t)(b * NPIX) + n0 + n) * 64 + part * 8;
    *(uint4*)dst = make_uint4(ph[0], ph[1], ph[2], ph[3]);
    *(uint4*)(dst + 32) = make_uint4(plo[0], plo[1], plo[2], plo[3]);
  }
}

// ---------------- K4: h projection (bf16 MFMA GEMM) ----------------
__global__ __launch_bounds__(256) void k_h(const u16* __restrict__ xT,
                                           const u16* __restrict__ Whbf,
                                           const float* __restrict__ bh,
                                           u16* __restrict__ h) {
  __shared__ u16 At[128 * 32];
  __shared__ u16 Bt[128 * 32];
  int blk = blockIdx.x;
  int b = blk >> 6, r = blk & 63;
  int nt = r >> 1, ot = r & 1;
  int n0 = nt * 128, o0 = ot * 128;
  int t = threadIdx.x, lane = t & 63, w = t >> 6;
  int wr = w >> 1, wc = w & 1;
  int coll = lane & 15, cg = lane >> 4;
  f32x4 acc[4][4] = {};
  for (int kc = 0; kc < 8; kc++) {
    __syncthreads();
#pragma unroll
    for (int r2 = 0; r2 < 2; r2++) {
      int s = r2 * 256 + t;
      int row = s >> 2, slot = s & 3;
      int sw = (row ^ (row >> 2)) & 3;
      uint4 va = *(const uint4*)(xT + ((size_t)(b * NPIX + n0 + row)) * NC + kc * 32 + slot * 8);
      *(uint4*)((char*)At + row * 64 + ((slot ^ sw) * 16)) = va;
      uint4 vb = *(const uint4*)(Whbf + (size_t)(o0 + row) * NC + kc * 32 + slot * 8);
      *(uint4*)((char*)Bt + row * 64 + ((slot ^ sw) * 16)) = vb;
    }
    __syncthreads();
    bfv8 af[4], bfr[4];
#pragma unroll
    for (int mi = 0; mi < 4; mi++) {
      int row = wr * 64 + mi * 16 + coll;
      int slot = cg ^ ((row ^ (row >> 2)) & 3);
      af[mi] = *(const bfv8*)((const char*)At + row * 64 + slot * 16);
    }
#pragma unroll
    for (int ni = 0; ni < 4; ni++) {
      int row = wc * 64 + ni * 16 + coll;
      int slot = cg ^ ((row ^ (row >> 2)) & 3);
      bfr[ni] = *(const bfv8*)((const char*)Bt + row * 64 + slot * 16);
    }
#pragma unroll
    for (int mi = 0; mi < 4; mi++)
#pragma unroll
      for (int ni = 0; ni < 4; ni++)
        acc[mi][ni] = __builtin_amdgcn_mfma_f32_16x16x32_bf16(af[mi], bfr[ni], acc[mi][ni], 0, 0, 0);
  }
#pragma unroll
  for (int ni = 0; ni < 4; ni++) {
    int o = o0 + wc * 64 + ni * 16 + coll;
    float bias = bh[o];
#pragma unroll
    for (int mi = 0; mi < 4; mi++) {
      int px = n0 + wr * 64 + mi * 16 + cg * 4;
      u32 lo = (u32)f2bf(acc[mi][ni][0] + bias) | ((u32)f2bf(acc[mi][ni][1] + bias) << 16);
      u32 hi = (u32)f2bf(acc[mi][ni][2] + bias) | ((u32)f2bf(acc[mi][ni][3] + bias) << 16);
      *(uint2*)(h + ((size_t)(b * NC + o)) * NPIX + px) = make_uint2(lo, hi);
    }
  }
}

// ---------------- K5: pass 1 — per j: M_j = max_i S'[j,i], Dinv_j ----------------
// S'[j,i] = sum_k f[k,j] g[k,i], via split-bf16 MFMA (3x)
__global__ __launch_bounds__(512) void k_pass1(const u16* __restrict__ fT,
                                               const u16* __restrict__ gT,
                                               float* __restrict__ Mrow,
                                               float* __restrict__ Dinv) {
  __shared__ u16 gs[2][64 * 64];  // per-iq staged g tile [64 i][32hi+32lo], swizzled
  __shared__ float pm[2][64], pd[2][64];
  int blk = blockIdx.x;
  int b = blk >> 6, j0 = (blk & 63) * 64;
  int t = threadIdx.x, lane = t & 63, w = t >> 6;
  int jt = w & 3, iq = w >> 2;
  int coll = lane & 15, cg = lane >> 4;
  // A-frags (f rows, fixed per wave)
  const u16* fr = fT + ((size_t)(b * NPIX) + j0 + jt * 16 + coll) * 64 + cg * 8;
  bfv8 ah = *(const bfv8*)fr;
  bfv8 al = *(const bfv8*)(fr + 32);
  float m[4] = {-3e38f, -3e38f, -3e38f, -3e38f}, d[4] = {0.f, 0.f, 0.f, 0.f};
  int bq = t >> 8, tt = t & 255;
  int r0 = tt >> 3, s0 = tt & 7;          // rows 0..31
  int r1 = 32 + (tt >> 3), s1 = tt & 7;   // rows 32..63
  uint4 v0, v1;
  {
    const u16* g0 = gT + ((size_t)(b * NPIX) + bq * 2048 + r0) * 64 + s0 * 8;
    const u16* g1 = gT + ((size_t)(b * NPIX) + bq * 2048 + r1) * 64 + s1 * 8;
    v0 = *(const uint4*)g0;
    v1 = *(const uint4*)g1;
  }
  for (int it = 0; it < 32; ++it) {
    __syncthreads();
    *(uint4*)(&gs[bq][r0 * 64 + ((s0 ^ (r0 & 7)) << 3)]) = v0;
    *(uint4*)(&gs[bq][r1 * 64 + ((s1 ^ (r1 & 7)) << 3)]) = v1;
    __syncthreads();
    if (it < 31) {
      const u16* g0 = gT + ((size_t)(b * NPIX) + bq * 2048 + (it + 1) * 64 + r0) * 64 + s0 * 8;
      const u16* g1 = gT + ((size_t)(b * NPIX) + bq * 2048 + (it + 1) * 64 + r1) * 64 + s1 * 8;
      v0 = *(const uint4*)g0;
      v1 = *(const uint4*)g1;
    }
    float sv[4][4];
#pragma unroll
    for (int t4 = 0; t4 < 4; ++t4) {
      int row = t4 * 16 + coll;
      const u16* base = &gs[iq][row * 64];
      bfv8 bh = *(const bfv8*)(base + ((cg ^ (row & 7)) << 3));
      bfv8 bl = *(const bfv8*)(base + (((4 + cg) ^ (row & 7)) << 3));
      f32x4 s = {0.f, 0.f, 0.f, 0.f};
      s = __builtin_amdgcn_mfma_f32_16x16x32_bf16(al, bh, s, 0, 0, 0);
      s = __builtin_amdgcn_mfma_f32_16x16x32_bf16(ah, bl, s, 0, 0, 0);
      s = __builtin_amdgcn_mfma_f32_16x16x32_bf16(ah, bh, s, 0, 0, 0);
      sv[t4][0] = s[0]; sv[t4][1] = s[1]; sv[t4][2] = s[2]; sv[t4][3] = s[3];
    }
#pragma unroll
    for (int r = 0; r < 4; ++r) {
      float ms = fmaxf(fmaxf(sv[0][r], sv[1][r]), fmaxf(sv[2][r], sv[3][r]));
      float nm = fmaxf(m[r], ms);
      d[r] = d[r] * __expf(m[r] - nm) + __expf(sv[0][r] - nm) + __expf(sv[1][r] - nm) +
             __expf(sv[2][r] - nm) + __expf(sv[3][r] - nm);
      m[r] = nm;
    }
  }
#pragma unroll
  for (int r = 0; r < 4; ++r) {
#pragma unroll
    for (int off = 1; off < 16; off <<= 1) {
      float m2 = __shfl_xor(m[r], off);
      float d2 = __shfl_xor(d[r], off);
      float nm = fmaxf(m[r], m2);
      d[r] = d[r] * __expf(m[r] - nm) + d2 * __expf(m2 - nm);
      m[r] = nm;
    }
  }
  if (coll == 0) {
#pragma unroll
    for (int r = 0; r < 4; ++r) {
      pm[iq][jt * 16 + cg * 4 + r] = m[r];
      pd[iq][jt * 16 + cg * 4 + r] = d[r];
    }
  }
  __syncthreads();
  if (t < 64) {
    float m0 = pm[0][t], m1 = pm[1][t];
    float nm = fmaxf(m0, m1);
    float dd = pd[0][t] * __expf(m0 - nm) + pd[1][t] * __expf(m1 - nm);
    Mrow[b * NPIX + j0 + t] = nm;
    Dinv[b * NPIX + j0 + t] = 1.0f / dd;
  }
}

// ---------------- K6: pass 2 — O[i,c] = sum_j P[j,i] h[c,j]; out = gamma*O + x ----------------
__global__ __launch_bounds__(256) void k_pass2(const u16* __restrict__ fT,
                                               const u16* __restrict__ gT,
                                               const u16* __restrict__ h,
                                               const float* __restrict__ Mrow,
                                               const float* __restrict__ Dinv,
                                               const float* __restrict__ x,
                                               const float* __restrict__ gamma,
                                               float* __restrict__ out) {
  __shared__ u16 vt[128 * 64];     // h tile [128 c][64 j], swizzled (16KB)
  __shared__ u16 pl[4][16 * 64];   // per-wave P^T [16 i][64 j], swizzled (8KB)
  __shared__ float md[2][64];
  __shared__ float tb[64][65];
  int blk = blockIdx.x;
  int b = blk >> 7;
  int r_ = blk & 127;
  int i0 = (r_ >> 1) * 64;
  int ch0 = (r_ & 1) * 128;
  int t = threadIdx.x, lane = t & 63, w = t >> 6;
  int coll = lane & 15, cg = lane >> 4;
  // g B-frags for this wave's i-subtile (fixed)
  const u16* gr = gT + ((size_t)(b * NPIX) + i0 + w * 16 + coll) * 64 + cg * 8;
  bfv8 gh = *(const bfv8*)gr;
  bfv8 gl = *(const bfv8*)(gr + 32);
  f32x4 acc[8] = {};
  uint4 hv[4];
  float mpre = 0.f, dpre = 0.f;
#pragma unroll
  for (int q = 0; q < 4; ++q) {
    int sidx = q * 256 + t;
    int row = sidx >> 3, slot = sidx & 7;
    hv[q] = *(const uint4*)(h + ((size_t)(b * NC) + ch0 + row) * NPIX + slot * 8);
  }
  if (t < 64) { mpre = Mrow[b * NPIX + t]; dpre = Dinv[b * NPIX + t]; }
  for (int jc = 0; jc < 64; ++jc) {
    int j0 = jc * 64;
    __syncthreads();
#pragma unroll
    for (int q = 0; q < 4; ++q) {
      int sidx = q * 256 + t;
      int row = sidx >> 3, slot = sidx & 7;
      *(uint4*)(&vt[row * 64 + ((slot ^ (row & 7)) << 3)]) = hv[q];
    }
    if (t < 64) { md[0][t] = mpre; md[1][t] = dpre; }
    __syncthreads();
    if (jc < 63) {
      int j1 = j0 + 64;
#pragma unroll
      for (int q = 0; q < 4; ++q) {
        int sidx = q * 256 + t;
        int row = sidx >> 3, slot = sidx & 7;
        hv[q] = *(const uint4*)(h + ((size_t)(b * NC) + ch0 + row) * NPIX + j1 + slot * 8);
      }
      if (t < 64) { mpre = Mrow[b * NPIX + j1 + t]; dpre = Dinv[b * NPIX + j1 + t]; }
    }
    // QK for 4 j-subtiles
    bfv8 ah[4], al[4];
#pragma unroll
    for (int jt2 = 0; jt2 < 4; ++jt2) {
      const u16* fr = fT + ((size_t)(b * NPIX) + j0 + jt2 * 16 + coll) * 64 + cg * 8;
      ah[jt2] = *(const bfv8*)fr;
      al[jt2] = *(const bfv8*)(fr + 32);
    }
#pragma unroll
    for (int jt2 = 0; jt2 < 4; ++jt2) {
      f32x4 s = {0.f, 0.f, 0.f, 0.f};
      s = __builtin_amdgcn_mfma_f32_16x16x32_bf16(al[jt2], gh, s, 0, 0, 0);
      s = __builtin_amdgcn_mfma_f32_16x16x32_bf16(ah[jt2], gl, s, 0, 0, 0);
      s = __builtin_amdgcn_mfma_f32_16x16x32_bf16(ah[jt2], gh, s, 0, 0, 0);
      u32 pk0, pk1;
      {
        int jr = jt2 * 16 + cg * 4;
        float p0 = __expf(s[0] - md[0][jr + 0]) * md[1][jr + 0];
        float p1 = __expf(s[1] - md[0][jr + 1]) * md[1][jr + 1];
        float p2 = __expf(s[2] - md[0][jr + 2]) * md[1][jr + 2];
        float p3 = __expf(s[3] - md[0][jr + 3]) * md[1][jr + 3];
        pk0 = (u32)f2bf(p0) | ((u32)f2bf(p1) << 16);
        pk1 = (u32)f2bf(p2) | ((u32)f2bf(p3) << 16);
      }
      char* pb = (char*)&pl[w][0] + coll * 128;
      *(uint2*)(pb + ((jt2 * 32 + cg * 8) ^ ((coll & 7) << 4))) = make_uint2(pk0, pk1);
    }
    // PV
    bfv8 pa[2];
#pragma unroll
    for (int kb = 0; kb < 2; ++kb) {
      const char* pb = (const char*)&pl[w][0] + coll * 128;
      pa[kb] = *(const bfv8*)(pb + ((kb * 64 + cg * 16) ^ ((coll & 7) << 4)));
    }
#pragma unroll
    for (int ct = 0; ct < 8; ++ct) {
      int row = ct * 16 + coll;
      const char* vb = (const char*)vt + row * 128;
      int sw = (row & 7) << 4;
#pragma unroll
      for (int kb = 0; kb < 2; ++kb) {
        bfv8 bv = *(const bfv8*)(vb + ((kb * 64 + cg * 16) ^ sw));
        acc[ct] = __builtin_amdgcn_mfma_f32_16x16x32_bf16(pa[kb], bv, acc[ct], 0, 0, 0);
      }
    }
  }
  // epilogue: transpose + gamma*sa + x
  float gam = gamma[0];
  for (int ch = 0; ch < 2; ++ch) {
    __syncthreads();
#pragma unroll
    for (int q2 = 0; q2 < 4; ++q2)
#pragma unroll
      for (int rr = 0; rr < 4; ++rr)
        tb[w * 16 + cg * 4 + rr][q2 * 16 + coll] = acc[ch * 4 + q2][rr];
    __syncthreads();
    int crow = t >> 2, part = t & 3;
    const float* xp = x + ((size_t)(b * NC) + ch0 + ch * 64 + crow) * NPIX + i0 + part * 16;
    float* op = out + ((size_t)(b * NC) + ch0 + ch * 64 + crow) * NPIX + i0 + part * 16;
#pragma unroll
    for (int v = 0; v < 4; ++v) {
      float4 xv = *(const float4*)(xp + v * 4);
      float4 ov;
      ov.x = gam * tb[part * 16 + v * 4 + 0][crow] + xv.x;
      ov.y = gam * tb[part * 16 + v * 4 + 1][crow] + xv.y;
      ov.z = gam * tb[part * 16 + v * 4 + 2][crow] + xv.z;
      ov.w = gam * tb[part * 16 + v * 4 + 3][crow] + xv.w;
      *(float4*)(op + v * 4) = ov;
    }
  }
}

extern "C" void kernel_launch(void* const* d_in, const int* in_sizes, int n_in,
                              void* d_out, int out_size, void* d_ws, size_t ws_size,
                              hipStream_t stream) {
  (void)in_sizes; (void)n_in; (void)out_size; (void)ws_size;
  const float* x = (const float*)d_in[0];
  const float* Wf = (const float*)d_in[1];
  const float* bf_ = (const float*)d_in[2];
  const float* Wg = (const float*)d_in[3];
  const float* bg_ = (const float*)d_in[4];
  const float* Wh = (const float*)d_in[5];
  const float* bh = (const float*)d_in[6];
  const float* gamma = (const float*)d_in[7];
  float* out = (float*)d_out;
  char* ws = (char*)d_ws;
  u16* xT = (u16*)ws;                                   // 8 MB
  u16* h = (u16*)(ws + (8u << 20));                     // 8 MB
  u16* fT = (u16*)(ws + (16u << 20));                   // 2 MB
  u16* gT = (u16*)(ws + (18u << 20));                   // 2 MB
  float* Mrow = (float*)(ws + (20u << 20));             // 64 KB
  float* Dinv = (float*)(ws + (20u << 20) + 65536);     // 64 KB
  u16* Whbf = (u16*)(ws + (20u << 20) + 131072);        // 128 KB

  k_convert_wh<<<64, 256, 0, stream>>>(Wh, Whbf);
  k_transpose<<<1024, 256, 0, stream>>>(x, xT);
  k_fg<<<256, 256, 0, stream>>>(x, Wf, bf_, Wg, bg_, fT, gT);
  k_h<<<256, 256, 0, stream>>>(xT, Whbf, bh, h);
  k_pass1<<<256, 512, 0, stream>>>(fT, gT, Mrow, Dinv);
  k_pass2<<<512, 256, 0, stream>>>(fT, gT, h, Mrow, Dinv, x, gamma, out);
}